// Round 2
// baseline (157.527 us; speedup 1.0000x reference)
//
#include <hip/hip_runtime.h>
#include <float.h>

#define Bb 2
#define Ll 256
#define Ss 384
#define Hh 768
#define Tc 16
#define Dc 50
#define WD 100
#define CV 128
#define NG 200     // 4*Dc gates
#define OUTC 968   // H + WD + 2*Dc

// ws layout (floats):
//   [0, 128)      minv partials
//   [128, ...)    xproj table [2][128][200], bias folded in

__device__ inline float tanh_fast(float x) {
    float e = __expf(2.f * x);
    return 1.f - 2.f / (e + 1.f);
}
__device__ inline float sigmoid_fast(float x) {
    return 1.f / (1.f + __expf(-x));
}

// ================= kernel 1: min partials | xproj =================
// grid 144: [0,128) min, [128,144) xproj

__global__ __launch_bounds__(256) void kernel1(
        const float* __restrict__ bert, const float* __restrict__ char_table,
        const float* __restrict__ Wih_f, const float* __restrict__ bih_f, const float* __restrict__ bhh_f,
        const float* __restrict__ Wih_b, const float* __restrict__ bih_b, const float* __restrict__ bhh_b,
        float* __restrict__ minp, float* __restrict__ xpt) {
    int blk = blockIdx.x, tid = threadIdx.x;
    if (blk < 128) {
        const int n4 = (Bb * Ss * Hh) / 4;       // 147456 float4
        const float4* b4 = (const float4*)bert;
        float m = FLT_MAX;
        for (int i = blk * 256 + tid; i < n4; i += 128 * 256) {
            float4 v = b4[i];
            m = fminf(m, fminf(fminf(v.x, v.y), fminf(v.z, v.w)));
        }
        #pragma unroll
        for (int off = 32; off; off >>= 1) m = fminf(m, __shfl_down(m, off, 64));
        __shared__ float red[4];
        if ((tid & 63) == 0) red[tid >> 6] = m;
        __syncthreads();
        if (tid == 0) minp[blk] = fminf(fminf(red[0], red[1]), fminf(red[2], red[3]));
    } else {
        int idx = blk - 128;            // dir*8 + cid-chunk
        int dir = idx >> 3, c0 = (idx & 7) * 16;
        const float* Wih = dir ? Wih_b : Wih_f;
        const float* bih = dir ? bih_b : bih_f;
        const float* bhh = dir ? bhh_b : bhh_f;
        __shared__ float ct[16][Dc];
        for (int e = tid; e < 16 * Dc; e += 256)
            ((float*)ct)[e] = char_table[c0 * Dc + e];
        __syncthreads();
        if (tid < NG) {
            float w[Dc];
            #pragma unroll
            for (int j = 0; j < Dc; j++) w[j] = Wih[tid * Dc + j];
            float bias = bih[tid] + bhh[tid];
            for (int cid = 0; cid < 16; cid++) {
                float a = bias;
                #pragma unroll
                for (int j = 0; j < Dc; j++) a += w[j] * ct[cid][j];
                xpt[(dir * CV + c0 + cid) * NG + tid] = a;
            }
        }
    }
}

// ================= kernel 2: LSTM | word_reps | embed =================
// grid 1472: [0,1024) lstm (n=blk>>1, dir=blk&1), [1024,1408) word, [1408,1472) embed
// LSTM: wave w owns gate group w (i/f/g~/o), lanes 0..49 = channels.
//       xproj staged in LDS (xg) -- no runtime-indexed register arrays (scratch!).
//       h lives in registers, broadcast via v_readlane; gs double-buffered
//       in LDS -> ONE barrier per step; state update redundant per wave.
// word: 8 l-rows per block

__global__ __launch_bounds__(256) void kernel2(
        const int* __restrict__ char_ids, const int* __restrict__ char_count,
        const float* __restrict__ Whh_f, const float* __restrict__ Whh_b,
        const float* __restrict__ xpt,
        const float* __restrict__ bert, const int* __restrict__ p2w,
        const float* __restrict__ minp,
        const int* __restrict__ word_ids, const float* __restrict__ word_table,
        float* __restrict__ out) {
    __shared__ __align__(16) char smem[16392];
    int blk = blockIdx.x, tid = threadIdx.x;

    if (blk < 1024) {
        // ---------------- char bi-LSTM ----------------
        float (*xg)[NG] = (float (*)[NG])smem;     // 16*200*4 = 12800 B
        float* gs  = (float*)(smem + 12800);       // 2 x 256 floats = 2048 B
        int*   scid = (int*)(smem + 14848);        // 64 B

        int n = blk >> 1, dir = blk & 1;
        const float* Whh = dir ? Whh_b : Whh_f;
        int w = tid >> 6, l = tid & 63;
        int lc = l < 50 ? l : 49;                  // clamp inactive lanes
        int grow = w * 50 + lc;                    // gate row this thread owns

        int len = char_count[n];
        if (len < 1) len = 1;
        if (tid < Tc) {
            int t = tid;
            int st = dir ? (t < len ? len - 1 - t : t) : t;   // bwd: reverse valid prefix
            scid[t] = char_ids[n * Tc + st];
        }
        __syncthreads();

        // stage xproj rows as float4 (row stride 200 floats = 800B, 16B aligned)
        for (int e = tid; e < Tc * (NG / 4); e += 256) {
            int t = e / 50, q = e - t * 50;
            ((float4*)xg[t])[q] = ((const float4*)&xpt[(dir * CV + scid[t]) * NG])[q];
        }
        // recurrent weight row -> regs (constant indices only)
        float wr[50];
        #pragma unroll
        for (int j = 0; j < 50; j++) wr[j] = Whh[grow * 50 + j];
        __syncthreads();

        float c = 0.f, h = 0.f, maxv = -FLT_MAX;
        for (int t = 0; t < Tc; t++) {
            // gate pre-activation: xg + dot(h_prev, wr) via readlane broadcast
            float g0 = xg[t][grow], g1 = 0.f;
            int hb = __float_as_int(h);
            #pragma unroll
            for (int j = 0; j < 50; j += 2) {
                g0 = fmaf(__int_as_float(__builtin_amdgcn_readlane(hb, j)),     wr[j],     g0);
                g1 = fmaf(__int_as_float(__builtin_amdgcn_readlane(hb, j + 1)), wr[j + 1], g1);
            }
            float g = g0 + g1;
            // this wave's activation (wave2 = cell gate -> tanh)
            float act = (w == 2) ? tanh_fast(g) : sigmoid_fast(g);
            float* gb = gs + (t & 1) * 256;
            gb[(w << 6) | l] = act;
            __syncthreads();                       // only barrier per step
            // every wave redundantly updates state (keeps h wave-local)
            float si = gb[lc];
            float sf = gb[64 + lc];
            float tg = gb[128 + lc];
            float so = gb[192 + lc];
            c = sf * c + si * tg;
            h = so * tanh_fast(c);
            if (t < len) maxv = fmaxf(maxv, h);    // ragged max
        }
        if (tid < 50)
            out[(size_t)n * OUTC + (Hh + WD) + dir * Dc + tid] = maxv;
    } else if (blk < 1408) {
        // ---------------- word_reps masked max, 8 rows/block ----------------
        float (*sacc)[8][128] = (float (*)[8][128])smem;  // 4 waves * 8 rows * 128 = 16384B
        float* sminv = (float*)(smem + 16384);

        if (tid < 64) {
            float m = fminf(minp[tid], minp[tid + 64]);
            #pragma unroll
            for (int off = 32; off; off >>= 1) m = fminf(m, __shfl_down(m, off, 64));
            if (tid == 0) *sminv = m;
        }
        int idx = blk - 1024;          // 0..383
        int hc  = idx % 6;             // h-chunk of 128
        int lt  = (idx / 6) & 31;      // l-tile of 8
        int b   = idx / 192;
        int l0  = lt * 8;
        int w    = tid >> 6;           // wave -> s range [w*96, w*96+96)
        int lane = tid & 63;
        int s0 = w * 96;

        // 96-bit row masks via 2 ballots -> 3 SGPRs per row
        const int* pm = p2w + ((size_t)(b * Ll + l0)) * Ss + s0;
        unsigned m0[8], m1[8], m2[8];
        #pragma unroll
        for (int r = 0; r < 8; r++) {
            unsigned long long b0 = __ballot(pm[r * Ss + lane] != 0);
            unsigned long long b1 = __ballot(lane < 32 ? (pm[r * Ss + 64 + lane] != 0) : false);
            m0[r] = __builtin_amdgcn_readfirstlane((unsigned)b0);
            m1[r] = __builtin_amdgcn_readfirstlane((unsigned)(b0 >> 32));
            m2[r] = __builtin_amdgcn_readfirstlane((unsigned)b1);
        }

        const float2* bb2 = (const float2*)(bert + (size_t)b * Ss * Hh) + hc * 64 + lane;
        float2 acc[8];
        #pragma unroll
        for (int r = 0; r < 8; r++) { acc[r].x = -FLT_MAX; acc[r].y = -FLT_MAX; }

        for (int jo = 0; jo < 96; jo += 8) {       // 12 groups of 8 loads in flight
            float2 v[8];
            #pragma unroll
            for (int k = 0; k < 8; k++) v[k] = bb2[(size_t)(s0 + jo + k) * 384];
            #pragma unroll
            for (int k = 0; k < 8; k++) {
                int j = jo + k;
                #pragma unroll
                for (int r = 0; r < 8; r++) {
                    unsigned bit = (j < 32 ? m0[r] >> j
                                 : j < 64 ? m1[r] >> (j - 32)
                                          : m2[r] >> (j - 64)) & 1u;
                    if (bit) {                     // wave-uniform scalar branch
                        acc[r].x = fmaxf(acc[r].x, v[k].x);
                        acc[r].y = fmaxf(acc[r].y, v[k].y);
                    }
                }
            }
        }
        #pragma unroll
        for (int r = 0; r < 8; r++)
            *(float2*)&sacc[w][r][lane * 2] = acc[r];
        __syncthreads();

        float mv = *sminv;
        for (int e = tid; e < 8 * 128; e += 256) {
            int r = e >> 7, cx = e & 127;
            float m = fmaxf(fmaxf(sacc[0][r][cx], sacc[1][r][cx]),
                            fmaxf(sacc[2][r][cx], sacc[3][r][cx]));
            if (m == -FLT_MAX) m = mv;             // fully-masked row -> global min fill
            out[((size_t)(b * Ll + l0 + r)) * OUTC + hc * 128 + cx] = m;
        }
    } else {
        // ---------------- word embedding gather ----------------
        for (int i = (blk - 1408) * 256 + tid; i < Bb * Ll * WD; i += 64 * 256) {
            int bl = i / WD, d = i - bl * WD;
            out[(size_t)bl * OUTC + Hh + d] = word_table[(size_t)word_ids[bl] * WD + d];
        }
    }
}

extern "C" void kernel_launch(void* const* d_in, const int* in_sizes, int n_in,
                              void* d_out, int out_size, void* d_ws, size_t ws_size,
                              hipStream_t stream) {
    const float* bert       = (const float*)d_in[0];
    const int*   p2w        = (const int*)d_in[1];
    const int*   word_ids   = (const int*)d_in[2];
    const int*   char_count = (const int*)d_in[3];
    const int*   char_ids   = (const int*)d_in[4];
    // d_in[5] token_masks_char: consistent with char_count, unused
    const float* word_table = (const float*)d_in[6];
    const float* char_table = (const float*)d_in[7];
    const float* Wih_f = (const float*)d_in[8];
    const float* Whh_f = (const float*)d_in[9];
    const float* bih_f = (const float*)d_in[10];
    const float* bhh_f = (const float*)d_in[11];
    const float* Wih_b = (const float*)d_in[12];
    const float* Whh_b = (const float*)d_in[13];
    const float* bih_b = (const float*)d_in[14];
    const float* bhh_b = (const float*)d_in[15];
    float* out = (float*)d_out;

    float* minp = (float*)d_ws;          // 128 floats
    float* xpt  = minp + 128;            // 2*128*200 floats

    kernel1<<<144, 256, 0, stream>>>(
        bert, char_table, Wih_f, bih_f, bhh_f, Wih_b, bih_b, bhh_b,
        minp, xpt);
    kernel2<<<1472, 256, 0, stream>>>(
        char_ids, char_count, Whh_f, Whh_b, xpt, bert, p2w, minp,
        word_ids, word_table, out);
}

// Round 3
// 150.704 us; speedup vs baseline: 1.0453x; 1.0453x over previous
//
#include <hip/hip_runtime.h>
#include <float.h>

#define Bb 2
#define Ll 256
#define Ss 384
#define Hh 768
#define Tc 16
#define Dc 50
#define WD 100
#define CV 128
#define NG 200     // 4*Dc gates
#define OUTC 968   // H + WD + 2*Dc

// ws layout (floats):
//   [0, 128)      minv partials
//   [128, ...)    xproj table [2][128][200], bias folded in

__device__ inline float tanh_fast(float x) {
    float e = __expf(2.f * x);
    return 1.f - 2.f / (e + 1.f);
}
__device__ inline float sigmoid_fast(float x) {
    return 1.f / (1.f + __expf(-x));
}

// ================= kernel 1: min partials | xproj =================
// grid 144: [0,128) min, [128,144) xproj

__global__ __launch_bounds__(256) void kernel1(
        const float* __restrict__ bert, const float* __restrict__ char_table,
        const float* __restrict__ Wih_f, const float* __restrict__ bih_f, const float* __restrict__ bhh_f,
        const float* __restrict__ Wih_b, const float* __restrict__ bih_b, const float* __restrict__ bhh_b,
        float* __restrict__ minp, float* __restrict__ xpt) {
    int blk = blockIdx.x, tid = threadIdx.x;
    if (blk < 128) {
        const int n4 = (Bb * Ss * Hh) / 4;       // 147456 float4
        const float4* b4 = (const float4*)bert;
        float m = FLT_MAX;
        for (int i = blk * 256 + tid; i < n4; i += 128 * 256) {
            float4 v = b4[i];
            m = fminf(m, fminf(fminf(v.x, v.y), fminf(v.z, v.w)));
        }
        #pragma unroll
        for (int off = 32; off; off >>= 1) m = fminf(m, __shfl_down(m, off, 64));
        __shared__ float red[4];
        if ((tid & 63) == 0) red[tid >> 6] = m;
        __syncthreads();
        if (tid == 0) minp[blk] = fminf(fminf(red[0], red[1]), fminf(red[2], red[3]));
    } else {
        int idx = blk - 128;            // dir*8 + cid-chunk
        int dir = idx >> 3, c0 = (idx & 7) * 16;
        const float* Wih = dir ? Wih_b : Wih_f;
        const float* bih = dir ? bih_b : bih_f;
        const float* bhh = dir ? bhh_b : bhh_f;
        __shared__ float ct[16][Dc];
        for (int e = tid; e < 16 * Dc; e += 256)
            ((float*)ct)[e] = char_table[c0 * Dc + e];
        __syncthreads();
        if (tid < NG) {
            float w[Dc];
            #pragma unroll
            for (int j = 0; j < Dc; j++) w[j] = Wih[tid * Dc + j];
            float bias = bih[tid] + bhh[tid];
            for (int cid = 0; cid < 16; cid++) {
                float a = bias;
                #pragma unroll
                for (int j = 0; j < Dc; j++) a += w[j] * ct[cid][j];
                xpt[(dir * CV + c0 + cid) * NG + tid] = a;
            }
        }
    }
}

// ================= kernel 2: LSTM | word_reps | embed =================
// grid 1472: [0,1024) lstm (n=blk>>1, dir=blk&1), [1024,1408) word, [1408,1472) embed
// LSTM: round-0 proven structure. tid<200 owns a gate row, w[52] in VGPRs,
//       h broadcast from LDS via float4 reads, tid<50 serial state update,
//       2 barriers/step. (Readlane/redundant-update variants forced the
//       compiler to demote the weight array to scratch -- VGPR_Count 32/40,
//       2x slower. Do not reintroduce without checking VGPR_Count >= 80.)
// word: 8 l-rows per block

__global__ __launch_bounds__(256) void kernel2(
        const int* __restrict__ char_ids, const int* __restrict__ char_count,
        const float* __restrict__ Whh_f, const float* __restrict__ Whh_b,
        const float* __restrict__ xpt,
        const float* __restrict__ bert, const int* __restrict__ p2w,
        const float* __restrict__ minp,
        const int* __restrict__ word_ids, const float* __restrict__ word_table,
        float* __restrict__ out) {
    __shared__ __align__(16) char smem[16392];
    int blk = blockIdx.x, tid = threadIdx.x;

    if (blk < 1024) {
        // ---------------- char bi-LSTM ----------------
        float (*xg)[NG] = (float (*)[NG])smem;            // 16*200*4 = 12800
        float* gs  = (float*)(smem + 12800);              // 800
        float* hs  = (float*)(smem + 13600);              // 208 (52 floats)
        int*   scid = (int*)(smem + 13808);               // 64

        int n = blk >> 1, dir = blk & 1;
        const float* Whh = dir ? Whh_b : Whh_f;

        int len = char_count[n];
        if (len < 1) len = 1;
        if (tid < Tc) {
            int t = tid;
            int st = dir ? (t < len ? len - 1 - t : t) : t;   // bwd: reverse valid prefix
            scid[t] = char_ids[n * Tc + st];
        }
        if (tid < 52) hs[tid] = 0.f;
        __syncthreads();

        // stage xproj rows as float4 (row stride 200 floats = 800B, 16B aligned)
        for (int e = tid; e < Tc * (NG / 4); e += 256) {
            int t = e / 50, q = e - t * 50;
            ((float4*)xg[t])[q] = ((const float4*)&xpt[(dir * CV + scid[t]) * NG])[q];
        }
        float w[52];
        if (tid < NG) {
            #pragma unroll
            for (int j = 0; j < Dc; j++) w[j] = Whh[tid * Dc + j];
            w[50] = 0.f; w[51] = 0.f;
        }
        __syncthreads();

        float c = 0.f, maxv = -FLT_MAX;
        for (int t = 0; t < Tc; t++) {
            if (tid < NG) {
                float g = xg[t][tid];
                #pragma unroll
                for (int j = 0; j < 52; j += 4) {
                    float4 hv = *(const float4*)&hs[j];   // broadcast reads
                    g += hv.x * w[j] + hv.y * w[j+1] + hv.z * w[j+2] + hv.w * w[j+3];
                }
                gs[tid] = g;
            }
            __syncthreads();
            if (tid < Dc) {
                float si = sigmoid_fast(gs[tid]);
                float sf = sigmoid_fast(gs[tid + 50]);
                float tg = tanh_fast(gs[tid + 100]);
                float so = sigmoid_fast(gs[tid + 150]);
                c = sf * c + si * tg;
                float h = so * tanh_fast(c);
                hs[tid] = h;
                if (t < len) maxv = fmaxf(maxv, h);       // ragged max
            }
            __syncthreads();
        }
        if (tid < Dc)
            out[(size_t)n * OUTC + (Hh + WD) + dir * Dc + tid] = maxv;
    } else if (blk < 1408) {
        // ---------------- word_reps masked max, 8 rows/block ----------------
        float (*sacc)[8][128] = (float (*)[8][128])smem;  // 4 waves * 8 rows * 128 = 16384B
        float* sminv = (float*)(smem + 16384);

        if (tid < 64) {
            float m = fminf(minp[tid], minp[tid + 64]);
            #pragma unroll
            for (int off = 32; off; off >>= 1) m = fminf(m, __shfl_down(m, off, 64));
            if (tid == 0) *sminv = m;
        }
        int idx = blk - 1024;          // 0..383
        int hc  = idx % 6;             // h-chunk of 128
        int lt  = (idx / 6) & 31;      // l-tile of 8
        int b   = idx / 192;
        int l0  = lt * 8;
        int w    = tid >> 6;           // wave -> s range [w*96, w*96+96)
        int lane = tid & 63;
        int s0 = w * 96;

        // 96-bit row masks via 2 ballots -> 3 SGPRs per row
        const int* pm = p2w + ((size_t)(b * Ll + l0)) * Ss + s0;
        unsigned m0[8], m1[8], m2[8];
        #pragma unroll
        for (int r = 0; r < 8; r++) {
            unsigned long long b0 = __ballot(pm[r * Ss + lane] != 0);
            unsigned long long b1 = __ballot(lane < 32 ? (pm[r * Ss + 64 + lane] != 0) : false);
            m0[r] = __builtin_amdgcn_readfirstlane((unsigned)b0);
            m1[r] = __builtin_amdgcn_readfirstlane((unsigned)(b0 >> 32));
            m2[r] = __builtin_amdgcn_readfirstlane((unsigned)b1);
        }

        const float2* bb2 = (const float2*)(bert + (size_t)b * Ss * Hh) + hc * 64 + lane;
        float2 acc[8];
        #pragma unroll
        for (int r = 0; r < 8; r++) { acc[r].x = -FLT_MAX; acc[r].y = -FLT_MAX; }

        for (int jo = 0; jo < 96; jo += 8) {       // 12 groups of 8 loads in flight
            float2 v[8];
            #pragma unroll
            for (int k = 0; k < 8; k++) v[k] = bb2[(size_t)(s0 + jo + k) * 384];
            #pragma unroll
            for (int k = 0; k < 8; k++) {
                int j = jo + k;
                #pragma unroll
                for (int r = 0; r < 8; r++) {
                    unsigned bit = (j < 32 ? m0[r] >> j
                                 : j < 64 ? m1[r] >> (j - 32)
                                          : m2[r] >> (j - 64)) & 1u;
                    if (bit) {                     // wave-uniform scalar branch
                        acc[r].x = fmaxf(acc[r].x, v[k].x);
                        acc[r].y = fmaxf(acc[r].y, v[k].y);
                    }
                }
            }
        }
        #pragma unroll
        for (int r = 0; r < 8; r++)
            *(float2*)&sacc[w][r][lane * 2] = acc[r];
        __syncthreads();

        float mv = *sminv;
        for (int e = tid; e < 8 * 128; e += 256) {
            int r = e >> 7, cx = e & 127;
            float m = fmaxf(fmaxf(sacc[0][r][cx], sacc[1][r][cx]),
                            fmaxf(sacc[2][r][cx], sacc[3][r][cx]));
            if (m == -FLT_MAX) m = mv;             // fully-masked row -> global min fill
            out[((size_t)(b * Ll + l0 + r)) * OUTC + hc * 128 + cx] = m;
        }
    } else {
        // ---------------- word embedding gather ----------------
        for (int i = (blk - 1408) * 256 + tid; i < Bb * Ll * WD; i += 64 * 256) {
            int bl = i / WD, d = i - bl * WD;
            out[(size_t)bl * OUTC + Hh + d] = word_table[(size_t)word_ids[bl] * WD + d];
        }
    }
}

extern "C" void kernel_launch(void* const* d_in, const int* in_sizes, int n_in,
                              void* d_out, int out_size, void* d_ws, size_t ws_size,
                              hipStream_t stream) {
    const float* bert       = (const float*)d_in[0];
    const int*   p2w        = (const int*)d_in[1];
    const int*   word_ids   = (const int*)d_in[2];
    const int*   char_count = (const int*)d_in[3];
    const int*   char_ids   = (const int*)d_in[4];
    // d_in[5] token_masks_char: consistent with char_count, unused
    const float* word_table = (const float*)d_in[6];
    const float* char_table = (const float*)d_in[7];
    const float* Wih_f = (const float*)d_in[8];
    const float* Whh_f = (const float*)d_in[9];
    const float* bih_f = (const float*)d_in[10];
    const float* bhh_f = (const float*)d_in[11];
    const float* Wih_b = (const float*)d_in[12];
    const float* Whh_b = (const float*)d_in[13];
    const float* bih_b = (const float*)d_in[14];
    const float* bhh_b = (const float*)d_in[15];
    float* out = (float*)d_out;

    float* minp = (float*)d_ws;          // 128 floats
    float* xpt  = minp + 128;            // 2*128*200 floats

    kernel1<<<144, 256, 0, stream>>>(
        bert, char_table, Wih_f, bih_f, bhh_f, Wih_b, bih_b, bhh_b,
        minp, xpt);
    kernel2<<<1472, 256, 0, stream>>>(
        char_ids, char_count, Whh_f, Whh_b, xpt, bert, p2w, minp,
        word_ids, word_table, out);
}

// Round 5
// 150.203 us; speedup vs baseline: 1.0488x; 1.0033x over previous
//
#include <hip/hip_runtime.h>
#include <float.h>

#define Bb 2
#define Ll 256
#define Ss 384
#define Hh 768
#define Tc 16
#define Dc 50
#define WD 100
#define CV 128
#define NG 200     // 4*Dc gates
#define OUTC 968   // H + WD + 2*Dc

// ws layout (floats):
//   [0, 128)      minv partials
//   [128, ...)    xproj table [2][128][200], bias folded in

__device__ inline float tanh_fast(float x) {
    float e = __expf(2.f * x);
    return 1.f - 2.f / (e + 1.f);
}
__device__ inline float sigmoid_fast(float x) {
    return 1.f / (1.f + __expf(-x));
}

// ================= kernel 1: min partials | xproj =================
// grid 144: [0,128) min, [128,144) xproj

__global__ __launch_bounds__(256) void kernel1(
        const float* __restrict__ bert, const float* __restrict__ char_table,
        const float* __restrict__ Wih_f, const float* __restrict__ bih_f, const float* __restrict__ bhh_f,
        const float* __restrict__ Wih_b, const float* __restrict__ bih_b, const float* __restrict__ bhh_b,
        float* __restrict__ minp, float* __restrict__ xpt) {
    int blk = blockIdx.x, tid = threadIdx.x;
    if (blk < 128) {
        const int n4 = (Bb * Ss * Hh) / 4;       // 147456 float4
        const float4* b4 = (const float4*)bert;
        float m = FLT_MAX;
        for (int i = blk * 256 + tid; i < n4; i += 128 * 256) {
            float4 v = b4[i];
            m = fminf(m, fminf(fminf(v.x, v.y), fminf(v.z, v.w)));
        }
        #pragma unroll
        for (int off = 32; off; off >>= 1) m = fminf(m, __shfl_down(m, off, 64));
        __shared__ float red[4];
        if ((tid & 63) == 0) red[tid >> 6] = m;
        __syncthreads();
        if (tid == 0) minp[blk] = fminf(fminf(red[0], red[1]), fminf(red[2], red[3]));
    } else {
        int idx = blk - 128;            // dir*8 + cid-chunk
        int dir = idx >> 3, c0 = (idx & 7) * 16;
        const float* Wih = dir ? Wih_b : Wih_f;
        const float* bih = dir ? bih_b : bih_f;
        const float* bhh = dir ? bhh_b : bhh_f;
        __shared__ float ct[16][Dc];
        for (int e = tid; e < 16 * Dc; e += 256)
            ((float*)ct)[e] = char_table[c0 * Dc + e];
        __syncthreads();
        if (tid < NG) {
            float w[Dc];
            #pragma unroll
            for (int j = 0; j < Dc; j++) w[j] = Wih[tid * Dc + j];
            float bias = bih[tid] + bhh[tid];
            for (int cid = 0; cid < 16; cid++) {
                float a = bias;
                #pragma unroll
                for (int j = 0; j < Dc; j++) a += w[j] * ct[cid][j];
                xpt[(dir * CV + c0 + cid) * NG + tid] = a;
            }
        }
    }
}

// ================= kernel 2: LSTM | word_reps | embed =================
// grid 1472: [0,1024) lstm (n=blk>>1, dir=blk&1), [1024,1408) word, [1408,1472) embed
// LSTM: tid<200 owns a gate row. Recurrent weights w[52] are PINNED in VGPRs
//       via per-element empty-asm keep-alive at the top of every timestep:
//       without it the allocator rematerializes all 52 global loads inside
//       the t-loop (VGPR_Count was 32-40 across three variants => ~680 MB of
//       L2 reload traffic + a per-step L2 latency chain; kernel2 62-72 us).
//       Gate activations applied in the 200-thread phase (each row knows its
//       own nonlinearity); the 50-lane serial phase is just c/h update.
// word: 8 l-rows per block

__global__ __launch_bounds__(256) void kernel2(
        const int* __restrict__ char_ids, const int* __restrict__ char_count,
        const float* __restrict__ Whh_f, const float* __restrict__ Whh_b,
        const float* __restrict__ xpt,
        const float* __restrict__ bert, const int* __restrict__ p2w,
        const float* __restrict__ minp,
        const int* __restrict__ word_ids, const float* __restrict__ word_table,
        float* __restrict__ out) {
    __shared__ __align__(16) char smem[16392];
    int blk = blockIdx.x, tid = threadIdx.x;

    if (blk < 1024) {
        // ---------------- char bi-LSTM ----------------
        float (*xg)[NG] = (float (*)[NG])smem;            // 16*200*4 = 12800
        float* gs  = (float*)(smem + 12800);              // 800
        float* hs  = (float*)(smem + 13600);              // 208 (52 floats)
        int*   scid = (int*)(smem + 13808);               // 64

        int n = blk >> 1, dir = blk & 1;
        const float* Whh = dir ? Whh_b : Whh_f;

        int len = char_count[n];
        if (len < 1) len = 1;
        if (tid < Tc) {
            int t = tid;
            int st = dir ? (t < len ? len - 1 - t : t) : t;   // bwd: reverse valid prefix
            scid[t] = char_ids[n * Tc + st];
        }
        if (tid < 52) hs[tid] = 0.f;
        __syncthreads();

        // stage xproj rows as float4 (row stride 200 floats = 800B, 16B aligned)
        for (int e = tid; e < Tc * (NG / 4); e += 256) {
            int t = e / 50, q = e - t * 50;
            ((float4*)xg[t])[q] = ((const float4*)&xpt[(dir * CV + scid[t]) * NG])[q];
        }
        // recurrent weight row -> regs, defined for ALL lanes (clamped row)
        int wrow = tid < NG ? tid : NG - 1;
        bool istanh = (tid >= 100 && tid < 150);          // cell-gate rows
        float w[52];
        #pragma unroll
        for (int j = 0; j < Dc; j++) w[j] = Whh[wrow * Dc + j];
        w[50] = 0.f; w[51] = 0.f;
        __syncthreads();

        float c = 0.f, maxv = -FLT_MAX;
        for (int t = 0; t < Tc; t++) {
            // pin weights in VGPRs: each empty asm is a def, so a post-barrier
            // rematerialized reload would be dead code (zero runtime cost)
            #pragma unroll
            for (int j = 0; j < 52; j++) asm volatile("" : "+v"(w[j]));
            if (tid < NG) {
                float g = xg[t][tid];
                #pragma unroll
                for (int j = 0; j < 52; j += 4) {
                    float4 hv = *(const float4*)&hs[j];   // broadcast reads
                    g += hv.x * w[j] + hv.y * w[j+1] + hv.z * w[j+2] + hv.w * w[j+3];
                }
                // activation in the wide phase
                gs[tid] = istanh ? tanh_fast(g) : sigmoid_fast(g);
            }
            __syncthreads();
            if (tid < Dc) {
                float si = gs[tid];
                float sf = gs[tid + 50];
                float tg = gs[tid + 100];
                float so = gs[tid + 150];
                c = sf * c + si * tg;
                float h = so * tanh_fast(c);
                hs[tid] = h;
                if (t < len) maxv = fmaxf(maxv, h);       // ragged max
            }
            __syncthreads();
        }
        if (tid < Dc)
            out[(size_t)n * OUTC + (Hh + WD) + dir * Dc + tid] = maxv;
    } else if (blk < 1408) {
        // ---------------- word_reps masked max, 8 rows/block ----------------
        float (*sacc)[8][128] = (float (*)[8][128])smem;  // 4 waves * 8 rows * 128 = 16384B
        float* sminv = (float*)(smem + 16384);

        if (tid < 64) {
            float m = fminf(minp[tid], minp[tid + 64]);
            #pragma unroll
            for (int off = 32; off; off >>= 1) m = fminf(m, __shfl_down(m, off, 64));
            if (tid == 0) *sminv = m;
        }
        int idx = blk - 1024;          // 0..383
        int hc  = idx % 6;             // h-chunk of 128
        int lt  = (idx / 6) & 31;      // l-tile of 8
        int b   = idx / 192;
        int l0  = lt * 8;
        int w    = tid >> 6;           // wave -> s range [w*96, w*96+96)
        int lane = tid & 63;
        int s0 = w * 96;

        // 96-bit row masks via 2 ballots -> 3 SGPRs per row
        const int* pm = p2w + ((size_t)(b * Ll + l0)) * Ss + s0;
        unsigned m0[8], m1[8], m2[8];
        #pragma unroll
        for (int r = 0; r < 8; r++) {
            unsigned long long b0 = __ballot(pm[r * Ss + lane] != 0);
            unsigned long long b1 = __ballot(lane < 32 ? (pm[r * Ss + 64 + lane] != 0) : false);
            m0[r] = __builtin_amdgcn_readfirstlane((unsigned)b0);
            m1[r] = __builtin_amdgcn_readfirstlane((unsigned)(b0 >> 32));
            m2[r] = __builtin_amdgcn_readfirstlane((unsigned)b1);
        }

        const float2* bb2 = (const float2*)(bert + (size_t)b * Ss * Hh) + hc * 64 + lane;
        float2 acc[8];
        #pragma unroll
        for (int r = 0; r < 8; r++) { acc[r].x = -FLT_MAX; acc[r].y = -FLT_MAX; }

        for (int jo = 0; jo < 96; jo += 8) {       // 12 groups of 8 loads in flight
            float2 v[8];
            #pragma unroll
            for (int k = 0; k < 8; k++) v[k] = bb2[(size_t)(s0 + jo + k) * 384];
            #pragma unroll
            for (int k = 0; k < 8; k++) {
                int j = jo + k;
                #pragma unroll
                for (int r = 0; r < 8; r++) {
                    unsigned bit = (j < 32 ? m0[r] >> j
                                 : j < 64 ? m1[r] >> (j - 32)
                                          : m2[r] >> (j - 64)) & 1u;
                    if (bit) {                     // wave-uniform scalar branch
                        acc[r].x = fmaxf(acc[r].x, v[k].x);
                        acc[r].y = fmaxf(acc[r].y, v[k].y);
                    }
                }
            }
        }
        #pragma unroll
        for (int r = 0; r < 8; r++)
            *(float2*)&sacc[w][r][lane * 2] = acc[r];
        __syncthreads();

        float mv = *sminv;
        for (int e = tid; e < 8 * 128; e += 256) {
            int r = e >> 7, cx = e & 127;
            float m = fmaxf(fmaxf(sacc[0][r][cx], sacc[1][r][cx]),
                            fmaxf(sacc[2][r][cx], sacc[3][r][cx]));
            if (m == -FLT_MAX) m = mv;             // fully-masked row -> global min fill
            out[((size_t)(b * Ll + l0 + r)) * OUTC + hc * 128 + cx] = m;
        }
    } else {
        // ---------------- word embedding gather ----------------
        for (int i = (blk - 1408) * 256 + tid; i < Bb * Ll * WD; i += 64 * 256) {
            int bl = i / WD, d = i - bl * WD;
            out[(size_t)bl * OUTC + Hh + d] = word_table[(size_t)word_ids[bl] * WD + d];
        }
    }
}

extern "C" void kernel_launch(void* const* d_in, const int* in_sizes, int n_in,
                              void* d_out, int out_size, void* d_ws, size_t ws_size,
                              hipStream_t stream) {
    const float* bert       = (const float*)d_in[0];
    const int*   p2w        = (const int*)d_in[1];
    const int*   word_ids   = (const int*)d_in[2];
    const int*   char_count = (const int*)d_in[3];
    const int*   char_ids   = (const int*)d_in[4];
    // d_in[5] token_masks_char: consistent with char_count, unused
    const float* word_table = (const float*)d_in[6];
    const float* char_table = (const float*)d_in[7];
    const float* Wih_f = (const float*)d_in[8];
    const float* Whh_f = (const float*)d_in[9];
    const float* bih_f = (const float*)d_in[10];
    const float* bhh_f = (const float*)d_in[11];
    const float* Wih_b = (const float*)d_in[12];
    const float* Whh_b = (const float*)d_in[13];
    const float* bih_b = (const float*)d_in[14];
    const float* bhh_b = (const float*)d_in[15];
    float* out = (float*)d_out;

    float* minp = (float*)d_ws;          // 128 floats
    float* xpt  = minp + 128;            // 2*128*200 floats

    kernel1<<<144, 256, 0, stream>>>(
        bert, char_table, Wih_f, bih_f, bhh_f, Wih_b, bih_b, bhh_b,
        minp, xpt);
    kernel2<<<1472, 256, 0, stream>>>(
        char_ids, char_count, Whh_f, Whh_b, xpt, bert, p2w, minp,
        word_ids, word_table, out);
}